// Round 7
// baseline (230.170 us; speedup 1.0000x reference)
//
#include <hip/hip_runtime.h>

#define D_FEAT 1024
#define NTOK   4096
#define SEQ    2048
#define NHEAD  16
#define DK     64
#define QSCALE 0.1803368801111204f  // 0.125 * log2(e)

typedef float          f32x4  __attribute__((ext_vector_type(4)));
typedef float          f32x16 __attribute__((ext_vector_type(16)));
typedef short          s16x8  __attribute__((ext_vector_type(8)));
typedef unsigned short u16x4  __attribute__((ext_vector_type(4)));

__device__ __forceinline__ unsigned short f2bf(float f) {
  union { float f; unsigned int u; } x; x.f = f;
  unsigned int r = x.u + 0x7fffu + ((x.u >> 16) & 1u);
  return (unsigned short)(r >> 16);
}
__device__ __forceinline__ unsigned short f2h(float f) {
  union { _Float16 h; unsigned short u; } x; x.h = (_Float16)f; return x.u;
}
__device__ __forceinline__ float h2f(unsigned short u) {
  union { _Float16 h; unsigned short u; } x; x.u = u; return (float)x.h;
}

__device__ __forceinline__ f32x4 mfma16(s16x8 a, s16x8 b, f32x4 c) {
  return __builtin_amdgcn_mfma_f32_16x16x32_bf16(a, b, c, 0, 0, 0);
}
__device__ __forceinline__ f32x16 mfma32(s16x8 a, s16x8 b, f32x16 c) {
  return __builtin_amdgcn_mfma_f32_32x32x16_bf16(a, b, c, 0, 0, 0);
}

// async global -> LDS, 16B per lane (dest = wave-uniform base + lane*16)
__device__ __forceinline__ void gload16(const void* g, void* l) {
  __builtin_amdgcn_global_load_lds(
      (const __attribute__((address_space(1))) void*)g,
      (__attribute__((address_space(3))) void*)l, 16, 0, 0);
}

// raw v_exp_f32 (single instruction; llvm's exp2f w/o fast-math expands ~6x)
__device__ __forceinline__ float fexp2(float x) {
  return __builtin_amdgcn_exp2f(x);
}

// pack two f32 -> one u32 of 2 bf16 (RNE)
__device__ __forceinline__ unsigned int cvtpk(float a, float b) {
  unsigned int r;
  asm("v_cvt_pk_bf16_f32 %0, %1, %2" : "=v"(r) : "v"(a), "v"(b));
  return r;
}
// exchange x's upper 32 lanes with y's lower 32 lanes
__device__ __forceinline__ void swap32(unsigned int& x, unsigned int& y) {
  asm("v_permlane32_swap_b32 %0, %1" : "+v"(x), "+v"(y));
}
__device__ __forceinline__ s16x8 mk8(unsigned int a, unsigned int b,
                                     unsigned int c, unsigned int d) {
  union { unsigned int u[4]; s16x8 v; } x;
  x.u[0] = a; x.u[1] = b; x.u[2] = c; x.u[3] = d; return x.v;
}

// ---------------- prep: cast q/k/v to bf16 AND transpose+cast weights ----------------
__global__ __launch_bounds__(256) void prep_kernel(
    const float* __restrict__ q, const float* __restrict__ k, const float* __restrict__ v,
    const float* __restrict__ Wq, const float* __restrict__ Wk,
    const float* __restrict__ Wv, const float* __restrict__ Wo,
    unsigned short* __restrict__ qb, unsigned short* __restrict__ kb,
    unsigned short* __restrict__ vb,
    unsigned short* __restrict__ WT, unsigned short* __restrict__ Wot)
{
  __shared__ float tile[32][33];
  const int bx = blockIdx.x, tid = threadIdx.x;
  if (bx < 12288) {
    int sel = bx >> 12;
    const float* src = sel == 0 ? q : (sel == 1 ? k : v);
    unsigned short* dst = sel == 0 ? qb : (sel == 1 ? kb : vb);
    size_t i = ((size_t)(bx & 4095) * 256 + tid) * 4;
    float4 f = *(const float4*)(src + i);
    u16x4 o; o.x = f2bf(f.x); o.y = f2bf(f.y); o.z = f2bf(f.z); o.w = f2bf(f.w);
    *(u16x4*)(dst + i) = o;
  } else {
    int t = bx - 12288;
    int z = t >> 10, rest = t & 1023;
    int bxt = rest & 31, byt = rest >> 5;
    const float* W = z == 0 ? Wq : z == 1 ? Wk : z == 2 ? Wv : Wo;
    unsigned short* T = (z < 3) ? (WT + (size_t)z * 1024 * 1024) : Wot;
    int tx = tid & 31, ty = tid >> 5;
    int n = bxt * 32 + tx;
    for (int i = 0; i < 4; ++i) {
      int kk = byt * 32 + ty + i * 8;
      tile[ty + i * 8][tx] = W[(size_t)kk * D_FEAT + n];
    }
    __syncthreads();
    int kk = byt * 32 + tx;
    for (int i = 0; i < 4; ++i) {
      int n2 = bxt * 32 + ty + i * 8;
      T[(size_t)n2 * D_FEAT + kk] = f2bf(tile[tx][ty + i * 8]);
    }
  }
}

// ---------------- fused QKV projection GEMM (BK=64) ----------------
__global__ __launch_bounds__(256, 3) void gemm_qkv(
    const unsigned short* __restrict__ qb, const unsigned short* __restrict__ kb,
    const unsigned short* __restrict__ vb, const unsigned short* __restrict__ WT,
    const float* __restrict__ bq, const float* __restrict__ bk, const float* __restrict__ bv,
    unsigned short* __restrict__ Qp, unsigned short* __restrict__ Kp, unsigned short* __restrict__ Vt)
{
  __shared__ __align__(16) unsigned short sAB[2 * 128 * 64];
  unsigned short* sA = sAB;
  unsigned short* sB = sAB + 128 * 64;
  const int tid = threadIdx.x;
  const int wave = tid >> 6, lane = tid & 63;
  const int quad = lane >> 4, l16 = lane & 15;
  const int wx = wave & 1, wy = wave >> 1;
  const int bx = blockIdx.x;
  const int chunk = bx >> 3;

  const unsigned short* rA;
  const unsigned short* rB;
  int m0, n0;
  if (chunk < 2) {
    m0 = blockIdx.y * 128; n0 = (bx & 7) * 128;
    rA = (chunk ? kb : qb) + (size_t)m0 * D_FEAT;
    rB = WT + (size_t)(chunk * 1024 + n0) * D_FEAT;
  } else {
    m0 = (bx & 7) * 128; n0 = blockIdx.y * 128;
    rA = WT + (size_t)(2048 + m0) * D_FEAT;
    rB = vb + (size_t)n0 * D_FEAT;
  }

  f32x4 acc[4][4];
  for (int mt = 0; mt < 4; ++mt)
    for (int nt = 0; nt < 4; ++nt) acc[mt][nt] = (f32x4){0.f, 0.f, 0.f, 0.f};

  const int rw8 = lane >> 3;
  const int cls = ((lane & 7) ^ (lane >> 3)) * 8;  // swizzled source chunk
  const int sw = l16 & 7;

  for (int k0 = 0; k0 < D_FEAT; k0 += 64) {
    __syncthreads();
    for (int j = 0; j < 4; ++j) {
      int ch = wave * 4 + j;
      gload16(rA + (size_t)(ch * 8 + rw8) * D_FEAT + k0 + cls, sA + ch * 512);
      gload16(rB + (size_t)(ch * 8 + rw8) * D_FEAT + k0 + cls, sB + ch * 512);
    }
    __syncthreads();
    s16x8 af[2][4], bfr[2][4];
    for (int kk = 0; kk < 2; ++kk) {
      int c = ((kk * 4 + quad) ^ sw) * 8;
      for (int mt = 0; mt < 4; ++mt)
        af[kk][mt] = *(const s16x8*)(sA + (wy * 64 + mt * 16 + l16) * 64 + c);
      for (int nt = 0; nt < 4; ++nt)
        bfr[kk][nt] = *(const s16x8*)(sB + (wx * 64 + nt * 16 + l16) * 64 + c);
    }
    for (int kk = 0; kk < 2; ++kk)
      for (int mt = 0; mt < 4; ++mt)
        for (int nt = 0; nt < 4; ++nt)
          acc[mt][nt] = mfma16(af[kk][mt], bfr[kk][nt], acc[mt][nt]);
  }

  if (chunk < 2) {
    const float* bias = chunk ? bk : bq;
    unsigned short* Cp = chunk ? Kp : Qp;
    const float scale = chunk == 0 ? QSCALE : 1.0f;
    for (int mt = 0; mt < 4; ++mt)
      for (int nt = 0; nt < 4; ++nt) {
        int col = n0 + wx * 64 + nt * 16 + l16;
        float bcol = bias[col];
        for (int r = 0; r < 4; ++r) {
          int row = m0 + wy * 64 + mt * 16 + quad * 4 + r;
          Cp[(size_t)row * D_FEAT + col] = f2bf((acc[mt][nt][r] + bcol) * scale);
        }
      }
  } else {
    for (int mt = 0; mt < 4; ++mt)
      for (int r = 0; r < 4; ++r) {
        float bfeat = bv[m0 + wy * 64 + mt * 16 + quad * 4 + r];
        for (int nt = 0; nt < 4; ++nt) acc[mt][nt][r] += bfeat;
      }
    unsigned short* tb = sAB;
    for (int p = 0; p < 2; ++p) {
      __syncthreads();
      if (wx == p) {
        for (int mt = 0; mt < 4; ++mt)
          for (int nt = 0; nt < 4; ++nt) {
            int tok_loc = nt * 16 + l16;
            for (int r = 0; r < 4; ++r) {
              int f_loc = wy * 64 + mt * 16 + quad * 4 + r;
              tb[f_loc * 72 + tok_loc] = f2bf(acc[mt][nt][r]);
            }
          }
      }
      __syncthreads();
      int n_base = n0 + p * 64;
      int b = n_base >> 11, tok0 = n_base & 2047;
      int ck = lane & 7;
      for (int j = 0; j < 4; ++j) {
        int f_loc = (wave * 4 + j) * 8 + rw8;
        int f = m0 + f_loc, hh = f >> 6, dv = f & 63;
        *(s16x8*)(Vt + ((size_t)(b * 16 + hh) * 64 + dv) * SEQ + tok0 + ck * 8) =
            *(const s16x8*)(tb + f_loc * 72 + ck * 8);
      }
    }
  }
}

// ---------------- out-projection GEMM + bias + residual (128x64 tiles, BK=64) ----------------
__global__ __launch_bounds__(256) void gemm_o(
    const unsigned short* __restrict__ A, const unsigned short* __restrict__ Bt,
    const float* __restrict__ bias, const float* __restrict__ resid,
    float* __restrict__ Cout)
{
  __shared__ __align__(16) unsigned short sA[128 * 64];
  __shared__ __align__(16) unsigned short sB[64 * 64];
  const int tid = threadIdx.x;
  const int wave = tid >> 6, lane = tid & 63;
  const int quad = lane >> 4, l16 = lane & 15;
  const int wx = wave & 1, wy = wave >> 1;
  const int n0 = blockIdx.x * 64, m0 = blockIdx.y * 128;

  f32x4 acc[4][2];
  for (int mt = 0; mt < 4; ++mt)
    for (int nt = 0; nt < 2; ++nt) acc[mt][nt] = (f32x4){0.f, 0.f, 0.f, 0.f};

  const int rw8 = lane >> 3;
  const int cls = ((lane & 7) ^ (lane >> 3)) * 8;
  const int sw = l16 & 7;

  for (int k0 = 0; k0 < D_FEAT; k0 += 64) {
    __syncthreads();
    for (int j = 0; j < 4; ++j) {
      int ch = wave * 4 + j;
      gload16(A + (size_t)(m0 + ch * 8 + rw8) * D_FEAT + k0 + cls, sA + ch * 512);
    }
    for (int j = 0; j < 2; ++j) {
      int ch = wave * 2 + j;
      gload16(Bt + (size_t)(n0 + ch * 8 + rw8) * D_FEAT + k0 + cls, sB + ch * 512);
    }
    __syncthreads();
    s16x8 af[2][4], bfr[2][2];
    for (int kk = 0; kk < 2; ++kk) {
      int c = ((kk * 4 + quad) ^ sw) * 8;
      for (int mt = 0; mt < 4; ++mt)
        af[kk][mt] = *(const s16x8*)(sA + (wy * 64 + mt * 16 + l16) * 64 + c);
      for (int nt = 0; nt < 2; ++nt)
        bfr[kk][nt] = *(const s16x8*)(sB + (wx * 32 + nt * 16 + l16) * 64 + c);
    }
    for (int kk = 0; kk < 2; ++kk)
      for (int mt = 0; mt < 4; ++mt)
        for (int nt = 0; nt < 2; ++nt)
          acc[mt][nt] = mfma16(af[kk][mt], bfr[kk][nt], acc[mt][nt]);
  }

  for (int mt = 0; mt < 4; ++mt)
    for (int nt = 0; nt < 2; ++nt) {
      int col = n0 + wx * 32 + nt * 16 + l16;
      float bcol = bias[col];
      for (int r = 0; r < 4; ++r) {
        int row = m0 + wy * 64 + mt * 16 + quad * 4 + r;
        Cout[(size_t)row * D_FEAT + col] =
            acc[mt][nt][r] + bcol + resid[(size_t)row * D_FEAT + col];
      }
    }
}

// ---------------- flash attention, split-S partial pass ----------------
// Cross-tile software pipeline on the VERIFIED r5 32-key tile: per step,
// QK(t) [MFMA] runs in the same scheduling region as softmax+PV(t-1)
// [VALU+MFMA] -- independent work the compiler interleaves, attacking the
// r5 finding that MFMA(29%) and VALU(34%) never overlap under lockstep
// phases. 4 buffers x 8KB (32KB): buf b is K-read at step b, V-read at
// step b+1, rewritten (tile b+4) at step b+2 -- the top-of-step barrier
// covers the V-late-read. Counted vmcnt: 2 loads/tile, vmcnt(2) steps
// 0..30, vmcnt(0) at step 31; barrier + sched_barrier(0) every step.
// K swizzle and r5's verified V quad-spread swizzle unchanged.
__global__ __launch_bounds__(256, 3) void flash_part(
    const unsigned short* __restrict__ Qp,
    const unsigned short* __restrict__ Kp,
    const unsigned short* __restrict__ Vt,
    unsigned short* __restrict__ Opart,   // [z][bh][tok][dv] fp16
    float* __restrict__ L)                // [z][bh][tok]
{
  // 4 buffers of 8 KB: K tile [32 keys][64 d] then V^T tile [64 dv][32 keys]
  __shared__ __align__(16) unsigned short sB4[4][4096];

  const int tid = threadIdx.x;
  const int wave = tid >> 6, lane = tid & 63;
  const int l32 = lane & 31, h = lane >> 5;

  const int blk = blockIdx.x;              // 1024 blocks
  const int xcd = blk & 7, jj = blk >> 3;
  const int grp = xcd * 8 + (jj >> 4);     // (bh,z) group 0..63
  const int q0 = (jj & 15) * 128;
  const int bh = grp & 31, z = grp >> 5;
  const int b = bh >> 4, hd = bh & 15;
  const int kbase = z * (SEQ / 2);
  const size_t base = (size_t)b * SEQ * D_FEAT + (size_t)hd * DK;
  const unsigned short* vt = Vt + (size_t)bh * 64 * SEQ;

  const int qrow = wave * 32 + l32;

  // ---- Q direct to registers (4x 16B per lane; chunk (2s+h) of row qrow)
  const unsigned short* qptr = Qp + base + (size_t)(q0 + qrow) * D_FEAT;
  s16x8 bq[4];
#pragma unroll
  for (int s = 0; s < 4; ++s)
    bq[s] = *(const s16x8*)(qptr + (2 * s + h) * 8);

  // ---- staging pointers (advance by constants each tile) -- r5-verified
  // K: row = tid>>3 (32 rows x 128B), slot = tid&7, src chunk XOR row&7
  const int krow = tid >> 3;
  const unsigned short* kPtr =
      Kp + base + (size_t)(kbase + krow) * D_FEAT + (((tid & 7) ^ (krow & 7)) * 8);
  // V: row = tid>>2 (64 rows x 64B), slot = tid&3, src chunk XOR (row>>1)&3
  const int vrow = tid >> 2;
  const unsigned short* vPtr =
      vt + (size_t)vrow * SEQ + kbase + (((tid & 3) ^ ((tid >> 3) & 3)) * 8);

  const int kdst = wave * 512;          // shorts; lane*16B added by HW
  // prologue: issue KV(0) -> buf0, KV(1) -> buf1 (2 loads per tile)
#pragma unroll
  for (int pb = 0; pb < 2; ++pb) {
    gload16(kPtr, &sB4[pb][kdst]);
    gload16(vPtr, &sB4[pb][2048 + kdst]);
    kPtr += 32 * D_FEAT; vPtr += 32;
  }

  f32x16 o0, o1, stE, stO;
#pragma unroll
  for (int r = 0; r < 16; ++r) { o0[r] = 0.f; o1[r] = 0.f; }
  float lsA = 0.f, lsB = 0.f;

  const int kxor = l32 & 7;          // K read chunk XOR (8 slots)
  const int vxor = (l32 >> 1) & 3;   // V read chunk XOR (4 slots, quad-spread)

  // QK of tile in BUF -> ST (r5-verified fragment math)
#define QK_TILE(BUF, ST)                                                       \
  {                                                                            \
    const unsigned short* bK = &sB4[BUF][0];                                   \
    _Pragma("unroll") for (int r = 0; r < 16; ++r) ST[r] = 0.f;                \
    __builtin_amdgcn_s_setprio(1);                                            \
    _Pragma("unroll") for (int s = 0; s < 4; ++s) {                            \
      s16x8 a = *(const s16x8*)(bK + l32 * 64 + (((2 * s + h) ^ kxor) * 8));   \
      ST = mfma32(a, bq[s], ST);                                               \
    }                                                                          \
    __builtin_amdgcn_s_setprio(0);                                            \
  }

  // softmax of ST + PV against V of BUFV (r5-verified fragment math)
#define SMPV_TILE(BUFV, ST)                                                    \
  {                                                                            \
    const unsigned short* bV = &sB4[BUFV][2048];                               \
    unsigned int c[8];                                                         \
    _Pragma("unroll") for (int i = 0; i < 8; ++i) {                            \
      float e0 = fexp2(ST[2 * i]);                                             \
      float e1 = fexp2(ST[2 * i + 1]);                                         \
      lsA += e0; lsB += e1;                                                    \
      c[i] = cvtpk(e0, e1);                                                    \
    }                                                                          \
    swap32(c[0], c[2]); swap32(c[1], c[3]);                                    \
    swap32(c[4], c[6]); swap32(c[5], c[7]);                                    \
    s16x8 bp0 = mk8(c[0], c[1], c[2], c[3]);  /* keys  0..15 */                \
    s16x8 bp1 = mk8(c[4], c[5], c[6], c[7]);  /* keys 16..31 */                \
    __builtin_amdgcn_s_setprio(1);                                            \
    _Pragma("unroll") for (int kk = 0; kk < 2; ++kk) {                         \
      int cs = ((2 * kk + h) ^ vxor) * 8;                                      \
      s16x8 av0 = *(const s16x8*)(bV + l32 * 32 + cs);                         \
      s16x8 av1 = *(const s16x8*)(bV + (32 + l32) * 32 + cs);                  \
      s16x8 bp = kk ? bp1 : bp0;                                               \
      o0 = mfma32(av0, bp, o0);                                                \
      o1 = mfma32(av1, bp, o1);                                                \
    }                                                                          \
    __builtin_amdgcn_s_setprio(0);                                            \
  }

  // fence + prefetch issue (tile CUR+2 into (CUR+2)&3)
#define SYNC2                                                                  \
  asm volatile("s_waitcnt vmcnt(2)" ::: "memory");                             \
  __builtin_amdgcn_s_barrier();                                               \
  __builtin_amdgcn_sched_barrier(0);
#define ISSUE(NXT)                                                             \
  gload16(kPtr, &sB4[NXT][kdst]);                                              \
  gload16(vPtr, &sB4[NXT][2048 + kdst]);                                       \
  kPtr += 32 * D_FEAT; vPtr += 32;

  // step 0 (peel): QK only
  SYNC2; ISSUE(2); QK_TILE(0, stE);
  // steps 1..3
  SYNC2; ISSUE(3); QK_TILE(1, stO); SMPV_TILE(0, stE);
  SYNC2; ISSUE(0); QK_TILE(2, stE); SMPV_TILE(1, stO);
  SYNC2; ISSUE(1); QK_TILE(3, stO); SMPV_TILE(2, stE);
  // steps 4..27: 6 groups of 4
  for (int g6 = 0; g6 < 6; ++g6) {
    SYNC2; ISSUE(2); QK_TILE(0, stE); SMPV_TILE(3, stO);
    SYNC2; ISSUE(3); QK_TILE(1, stO); SMPV_TILE(0, stE);
    SYNC2; ISSUE(0); QK_TILE(2, stE); SMPV_TILE(1, stO);
    SYNC2; ISSUE(1); QK_TILE(3, stO); SMPV_TILE(2, stE);
  }
  // step 28 (issues tile 30), step 29 (issues tile 31)
  SYNC2; ISSUE(2); QK_TILE(0, stE); SMPV_TILE(3, stO);
  SYNC2; ISSUE(3); QK_TILE(1, stO); SMPV_TILE(0, stE);
  // step 30: no issue (tiles 30,31 in flight; vmcnt(2) drains tile 30)
  SYNC2;           QK_TILE(2, stE); SMPV_TILE(1, stO);
  // step 31: full drain (tile 31 arrived for all waves after barrier)
  asm volatile("s_waitcnt vmcnt(0)" ::: "memory");
  __builtin_amdgcn_s_barrier();
  __builtin_amdgcn_sched_barrier(0);
  QK_TILE(3, stO); SMPV_TILE(2, stE);
  // epilogue step: softmax+PV of tile 31 (buf 3); no rewrite follows
  SMPV_TILE(3, stO);
#undef QK_TILE
#undef SMPV_TILE
#undef SYNC2
#undef ISSUE

  // epilogue: unnormalized O^T (fp16) + l (one cross-half shuffle total)
  float lsum = lsA + lsB;
  lsum += __shfl_xor(lsum, 32, 64);
  const size_t trow = (size_t)(z * 32 + bh) * SEQ + (q0 + qrow);
  unsigned short* orow = Opart + trow * 64;
#pragma unroll
  for (int g = 0; g < 4; ++g) {
    u16x4 ov;
    for (int r = 0; r < 4; ++r) ov[r] = f2h(o0[4 * g + r]);
    *(u16x4*)(orow + 8 * g + 4 * h) = ov;
  }
#pragma unroll
  for (int g = 0; g < 4; ++g) {
    u16x4 ov;
    for (int r = 0; r < 4; ++r) ov[r] = f2h(o1[4 * g + r]);
    *(u16x4*)(orow + 32 + 8 * g + 4 * h) = ov;
  }
  if (h == 0) L[trow] = lsum;
}

// ---------------- combine the two key-halves -> ctx (bf16) ----------------
__global__ __launch_bounds__(256) void combine_kernel(
    const unsigned short* __restrict__ Opart, const float* __restrict__ L,
    unsigned short* __restrict__ ctx)
{
  const int idx = blockIdx.x * 256 + threadIdx.x;   // 1M total
  const int dq = idx & 15;                          // dv group of 4
  const int trow = idx >> 4;                        // bh*SEQ + tok
  const int bh = trow >> 11, tok = trow & 2047;
  const int b = bh >> 4, h = bh & 15;
  const int HS = 32 * SEQ;                          // half stride (rows)

  float inv = __builtin_amdgcn_rcpf(L[trow] + L[HS + trow]);

  u16x4 p0 = *(const u16x4*)(Opart + (size_t)trow * 64 + dq * 4);
  u16x4 p1 = *(const u16x4*)(Opart + ((size_t)HS + trow) * 64 + dq * 4);
  u16x4 o;
  for (int r = 0; r < 4; ++r)
    o[r] = f2bf((h2f(p0[r]) + h2f(p1[r])) * inv);
  *(u16x4*)(ctx + (size_t)b * SEQ * D_FEAT + (size_t)tok * D_FEAT + h * 64 + dq * 4) = o;
}

// ---------------- LayerNorm over last dim (1024) ----------------
__global__ __launch_bounds__(256) void ln_kernel(
    const float* __restrict__ x, const float* __restrict__ gamma,
    const float* __restrict__ beta, float* __restrict__ out)
{
  const int row = blockIdx.x, tid = threadIdx.x;
  const int wave = tid >> 6, lane = tid & 63;
  const float* xr = x + (size_t)row * D_FEAT;
  float4 v = ((const float4*)xr)[tid];
  float s  = v.x + v.y + v.z + v.w;
  float ss = v.x * v.x + v.y * v.y + v.z * v.z + v.w * v.w;
  for (int off = 1; off < 64; off <<= 1) {
    s  += __shfl_xor(s,  off, 64);
    ss += __shfl_xor(ss, off, 64);
  }
  __shared__ float red[8];
  if (lane == 0) { red[wave] = s; red[wave + 4] = ss; }
  __syncthreads();
  s  = red[0] + red[1] + red[2] + red[3];
  ss = red[4] + red[5] + red[6] + red[7];
  float mean = s * (1.f / D_FEAT);
  float var  = ss * (1.f / D_FEAT) - mean * mean;
  float rstd = rsqrtf(var + 1e-6f);
  float4 g  = ((const float4*)gamma)[tid];
  float4 bt = ((const float4*)beta)[tid];
  float4 o;
  o.x = (v.x - mean) * rstd * g.x + bt.x;
  o.y = (v.y - mean) * rstd * g.y + bt.y;
  o.z = (v.z - mean) * rstd * g.z + bt.z;
  o.w = (v.w - mean) * rstd * g.w + bt.w;
  ((float4*)(out + (size_t)row * D_FEAT))[tid] = o;
}

extern "C" void kernel_launch(void* const* d_in, const int* in_sizes, int n_in,
                              void* d_out, int out_size, void* d_ws, size_t ws_size,
                              hipStream_t stream) {
  const float* q     = (const float*)d_in[0];
  const float* k     = (const float*)d_in[1];
  const float* v     = (const float*)d_in[2];
  const float* Wq    = (const float*)d_in[3];
  const float* bq    = (const float*)d_in[4];
  const float* Wk    = (const float*)d_in[5];
  const float* bk    = (const float*)d_in[6];
  const float* Wv    = (const float*)d_in[7];
  const float* bv    = (const float*)d_in[8];
  const float* Wo    = (const float*)d_in[9];
  const float* bo    = (const float*)d_in[10];
  const float* gamma = (const float*)d_in[11];
  const float* beta  = (const float*)d_in[12];

  char* w = (char*)d_ws;
  const size_t MB = 1u << 20;
  unsigned short* qb    = (unsigned short*)(w + 0 * MB);
  unsigned short* kb    = (unsigned short*)(w + 8 * MB);
  unsigned short* vb    = (unsigned short*)(w + 16 * MB);
  unsigned short* WT    = (unsigned short*)(w + 24 * MB);
  unsigned short* Wot   = (unsigned short*)(w + 30 * MB);
  unsigned short* Qp    = (unsigned short*)(w + 32 * MB);
  unsigned short* Kp    = (unsigned short*)(w + 40 * MB);
  unsigned short* Vt    = (unsigned short*)(w + 48 * MB);  // [bh][dv][tok]
  unsigned short* ctx   = (unsigned short*)(w + 56 * MB);
  float*          tmp   = (float*)(w + 64 * MB);           // 16 MB
  unsigned short* Opart = (unsigned short*)(w + 0 * MB);   // 16 MB fp16 (aliases qb/kb)
  float*          L     = (float*)(w + 16 * MB);           // 0.5 MB (aliases vb)

  prep_kernel<<<16384, 256, 0, stream>>>(q, k, v, Wq, Wk, Wv, Wo, qb, kb, vb, WT, Wot);

  gemm_qkv<<<dim3(24, 32), 256, 0, stream>>>(qb, kb, vb, WT, bq, bk, bv, Qp, Kp, Vt);

  flash_part<<<1024, 256, 0, stream>>>(Qp, Kp, Vt, Opart, L);

  combine_kernel<<<4096, 256, 0, stream>>>(Opart, L, ctx);

  gemm_o<<<dim3(16, 32), 256, 0, stream>>>(ctx, Wot, bo, v, tmp);

  ln_kernel<<<NTOK, 256, 0, stream>>>(tmp, gamma, beta, (float*)d_out);
}

// Round 9
// 227.806 us; speedup vs baseline: 1.0104x; 1.0104x over previous
//
#include <hip/hip_runtime.h>

#define D_FEAT 1024
#define NTOK   4096
#define SEQ    2048
#define NHEAD  16
#define DK     64
#define QSCALE 0.1803368801111204f  // 0.125 * log2(e)

typedef float          f32x4  __attribute__((ext_vector_type(4)));
typedef float          f32x16 __attribute__((ext_vector_type(16)));
typedef short          s16x8  __attribute__((ext_vector_type(8)));
typedef unsigned short u16x4  __attribute__((ext_vector_type(4)));

__device__ __forceinline__ unsigned short f2bf(float f) {
  union { float f; unsigned int u; } x; x.f = f;
  unsigned int r = x.u + 0x7fffu + ((x.u >> 16) & 1u);
  return (unsigned short)(r >> 16);
}
__device__ __forceinline__ unsigned short f2h(float f) {
  union { _Float16 h; unsigned short u; } x; x.h = (_Float16)f; return x.u;
}
__device__ __forceinline__ float h2f(unsigned short u) {
  union { _Float16 h; unsigned short u; } x; x.u = u; return (float)x.h;
}

__device__ __forceinline__ f32x4 mfma16(s16x8 a, s16x8 b, f32x4 c) {
  return __builtin_amdgcn_mfma_f32_16x16x32_bf16(a, b, c, 0, 0, 0);
}
__device__ __forceinline__ f32x16 mfma32(s16x8 a, s16x8 b, f32x16 c) {
  return __builtin_amdgcn_mfma_f32_32x32x16_bf16(a, b, c, 0, 0, 0);
}

// async global -> LDS, 16B per lane (dest = wave-uniform base + lane*16)
__device__ __forceinline__ void gload16(const void* g, void* l) {
  __builtin_amdgcn_global_load_lds(
      (const __attribute__((address_space(1))) void*)g,
      (__attribute__((address_space(3))) void*)l, 16, 0, 0);
}

// raw v_exp_f32 (single instruction; llvm's exp2f w/o fast-math expands ~6x)
__device__ __forceinline__ float fexp2(float x) {
  return __builtin_amdgcn_exp2f(x);
}

// pack two f32 -> one u32 of 2 bf16 (RNE)
__device__ __forceinline__ unsigned int cvtpk(float a, float b) {
  unsigned int r;
  asm("v_cvt_pk_bf16_f32 %0, %1, %2" : "=v"(r) : "v"(a), "v"(b));
  return r;
}
// exchange x's upper 32 lanes with y's lower 32 lanes
__device__ __forceinline__ void swap32(unsigned int& x, unsigned int& y) {
  asm("v_permlane32_swap_b32 %0, %1" : "+v"(x), "+v"(y));
}
__device__ __forceinline__ s16x8 mk8(unsigned int a, unsigned int b,
                                     unsigned int c, unsigned int d) {
  union { unsigned int u[4]; s16x8 v; } x;
  x.u[0] = a; x.u[1] = b; x.u[2] = c; x.u[3] = d; return x.v;
}

// ---------------- prep: cast q/k/v to bf16 AND transpose+cast weights ----------------
__global__ __launch_bounds__(256) void prep_kernel(
    const float* __restrict__ q, const float* __restrict__ k, const float* __restrict__ v,
    const float* __restrict__ Wq, const float* __restrict__ Wk,
    const float* __restrict__ Wv, const float* __restrict__ Wo,
    unsigned short* __restrict__ qb, unsigned short* __restrict__ kb,
    unsigned short* __restrict__ vb,
    unsigned short* __restrict__ WT, unsigned short* __restrict__ Wot)
{
  __shared__ float tile[32][33];
  const int bx = blockIdx.x, tid = threadIdx.x;
  if (bx < 12288) {
    int sel = bx >> 12;
    const float* src = sel == 0 ? q : (sel == 1 ? k : v);
    unsigned short* dst = sel == 0 ? qb : (sel == 1 ? kb : vb);
    size_t i = ((size_t)(bx & 4095) * 256 + tid) * 4;
    float4 f = *(const float4*)(src + i);
    u16x4 o; o.x = f2bf(f.x); o.y = f2bf(f.y); o.z = f2bf(f.z); o.w = f2bf(f.w);
    *(u16x4*)(dst + i) = o;
  } else {
    int t = bx - 12288;
    int z = t >> 10, rest = t & 1023;
    int bxt = rest & 31, byt = rest >> 5;
    const float* W = z == 0 ? Wq : z == 1 ? Wk : z == 2 ? Wv : Wo;
    unsigned short* T = (z < 3) ? (WT + (size_t)z * 1024 * 1024) : Wot;
    int tx = tid & 31, ty = tid >> 5;
    int n = bxt * 32 + tx;
    for (int i = 0; i < 4; ++i) {
      int kk = byt * 32 + ty + i * 8;
      tile[ty + i * 8][tx] = W[(size_t)kk * D_FEAT + n];
    }
    __syncthreads();
    int kk = byt * 32 + tx;
    for (int i = 0; i < 4; ++i) {
      int n2 = bxt * 32 + ty + i * 8;
      T[(size_t)n2 * D_FEAT + kk] = f2bf(tile[tx][ty + i * 8]);
    }
  }
}

// ---------------- fused QKV projection GEMM (BK=64) ----------------
// Counted-vmcnt double-buffer (r4-verified schedule class): prologue issues
// tiles 0,1; per step wait vmcnt(8) (own tile's 8 loads done, next tile's 8
// stay in flight -- no full drain), raw s_barrier + sched_barrier(0),
// compute, barrier, issue t+2 into the freed buffer. Fragment math,
// swizzles and epilogues identical to the verified 2-syncthreads version.
// Hazard ledger: post-COMP barrier orders all waves' buf reads before the
// rewrite; vmcnt decrements in issue order so vmcnt(8) retires exactly the
// current tile's 8 loads; barrier counts are wave-uniform (no divergence).
__global__ __launch_bounds__(256, 2) void gemm_qkv(
    const unsigned short* __restrict__ qb, const unsigned short* __restrict__ kb,
    const unsigned short* __restrict__ vb, const unsigned short* __restrict__ WT,
    const float* __restrict__ bq, const float* __restrict__ bk, const float* __restrict__ bv,
    unsigned short* __restrict__ Qp, unsigned short* __restrict__ Kp, unsigned short* __restrict__ Vt)
{
  __shared__ __align__(16) unsigned short sAB[2][2 * 128 * 64];  // 2 bufs x 32KB
  const int tid = threadIdx.x;
  const int wave = tid >> 6, lane = tid & 63;
  const int quad = lane >> 4, l16 = lane & 15;
  const int wx = wave & 1, wy = wave >> 1;
  const int bx = blockIdx.x;
  const int chunk = bx >> 3;

  const unsigned short* rA;
  const unsigned short* rB;
  int m0, n0;
  if (chunk < 2) {
    m0 = blockIdx.y * 128; n0 = (bx & 7) * 128;
    rA = (chunk ? kb : qb) + (size_t)m0 * D_FEAT;
    rB = WT + (size_t)(chunk * 1024 + n0) * D_FEAT;
  } else {
    m0 = (bx & 7) * 128; n0 = blockIdx.y * 128;
    rA = WT + (size_t)(2048 + m0) * D_FEAT;
    rB = vb + (size_t)n0 * D_FEAT;
  }

  f32x4 acc[4][4];
  for (int mt = 0; mt < 4; ++mt)
    for (int nt = 0; nt < 4; ++nt) acc[mt][nt] = (f32x4){0.f, 0.f, 0.f, 0.f};

  const int rw8 = lane >> 3;
  const int cls = ((lane & 7) ^ (lane >> 3)) * 8;  // swizzled source chunk
  const int sw = l16 & 7;

#define QKV_ISSUE(BUF, K0)                                                     \
  _Pragma("unroll") for (int j = 0; j < 4; ++j) {                              \
    int ch = wave * 4 + j;                                                     \
    gload16(rA + (size_t)(ch * 8 + rw8) * D_FEAT + (K0) + cls,                 \
            &sAB[BUF][ch * 512]);                                              \
    gload16(rB + (size_t)(ch * 8 + rw8) * D_FEAT + (K0) + cls,                 \
            &sAB[BUF][128 * 64 + ch * 512]);                                   \
  }

#define QKV_COMP(BUF)                                                         \
  {                                                                            \
    const unsigned short* sA = &sAB[BUF][0];                                   \
    const unsigned short* sB = &sAB[BUF][128 * 64];                            \
    s16x8 af[2][4], bfr[2][4];                                                 \
    _Pragma("unroll") for (int kk = 0; kk < 2; ++kk) {                         \
      int c = ((kk * 4 + quad) ^ sw) * 8;                                      \
      _Pragma("unroll") for (int mt = 0; mt < 4; ++mt)                         \
        af[kk][mt] = *(const s16x8*)(sA + (wy * 64 + mt * 16 + l16) * 64 + c); \
      _Pragma("unroll") for (int nt = 0; nt < 4; ++nt)                         \
        bfr[kk][nt] = *(const s16x8*)(sB + (wx * 64 + nt * 16 + l16) * 64 + c);\
    }                                                                          \
    _Pragma("unroll") for (int kk = 0; kk < 2; ++kk)                           \
      _Pragma("unroll") for (int mt = 0; mt < 4; ++mt)                         \
        _Pragma("unroll") for (int nt = 0; nt < 4; ++nt)                       \
          acc[mt][nt] = mfma16(af[kk][mt], bfr[kk][nt], acc[mt][nt]);          \
  }

#define GSYNC(N)                                                               \
  asm volatile("s_waitcnt vmcnt(" #N ")" ::: "memory");                        \
  __builtin_amdgcn_s_barrier();                                               \
  __builtin_amdgcn_sched_barrier(0);

  // prologue: tiles 0,1
  QKV_ISSUE(0, 0);
  QKV_ISSUE(1, 64);
  // steps 0..13 (issue t+2 = tiles 2..15)
  for (int t2 = 0; t2 < 14; t2 += 2) {
    GSYNC(8);
    QKV_COMP(0);
    __builtin_amdgcn_s_barrier();     // all waves done reading buf0
    __builtin_amdgcn_sched_barrier(0);
    QKV_ISSUE(0, (t2 + 2) * 64);
    GSYNC(8);
    QKV_COMP(1);
    __builtin_amdgcn_s_barrier();
    __builtin_amdgcn_sched_barrier(0);
    QKV_ISSUE(1, (t2 + 3) * 64);
  }
  // step 14: tiles 14,15 in flight; vmcnt(8) -> tile 14 ready; no issue
  GSYNC(8);
  QKV_COMP(0);
  // step 15: final drain
  GSYNC(0);
  QKV_COMP(1);
#undef QKV_ISSUE
#undef QKV_COMP
#undef GSYNC

  if (chunk < 2) {
    const float* bias = chunk ? bk : bq;
    unsigned short* Cp = chunk ? Kp : Qp;
    const float scale = chunk == 0 ? QSCALE : 1.0f;
    for (int mt = 0; mt < 4; ++mt)
      for (int nt = 0; nt < 4; ++nt) {
        int col = n0 + wx * 64 + nt * 16 + l16;
        float bcol = bias[col];
        for (int r = 0; r < 4; ++r) {
          int row = m0 + wy * 64 + mt * 16 + quad * 4 + r;
          Cp[(size_t)row * D_FEAT + col] = f2bf((acc[mt][nt][r] + bcol) * scale);
        }
      }
  } else {
    for (int mt = 0; mt < 4; ++mt)
      for (int r = 0; r < 4; ++r) {
        float bfeat = bv[m0 + wy * 64 + mt * 16 + quad * 4 + r];
        for (int nt = 0; nt < 4; ++nt) acc[mt][nt][r] += bfeat;
      }
    unsigned short* tb = &sAB[0][0];
    for (int p = 0; p < 2; ++p) {
      __syncthreads();
      if (wx == p) {
        for (int mt = 0; mt < 4; ++mt)
          for (int nt = 0; nt < 4; ++nt) {
            int tok_loc = nt * 16 + l16;
            for (int r = 0; r < 4; ++r) {
              int f_loc = wy * 64 + mt * 16 + quad * 4 + r;
              tb[f_loc * 72 + tok_loc] = f2bf(acc[mt][nt][r]);
            }
          }
      }
      __syncthreads();
      int n_base = n0 + p * 64;
      int b = n_base >> 11, tok0 = n_base & 2047;
      int ck = lane & 7;
      for (int j = 0; j < 4; ++j) {
        int f_loc = (wave * 4 + j) * 8 + rw8;
        int f = m0 + f_loc, hh = f >> 6, dv = f & 63;
        *(s16x8*)(Vt + ((size_t)(b * 16 + hh) * 64 + dv) * SEQ + tok0 + ck * 8) =
            *(const s16x8*)(tb + f_loc * 72 + ck * 8);
      }
    }
  }
}

// ---------------- out-projection GEMM + bias + residual (128x64 tiles, BK=64) ----------------
// Same counted-vmcnt double-buffer transform: 6 loads/tile, vmcnt(6).
__global__ __launch_bounds__(256) void gemm_o(
    const unsigned short* __restrict__ A, const unsigned short* __restrict__ Bt,
    const float* __restrict__ bias, const float* __restrict__ resid,
    float* __restrict__ Cout)
{
  __shared__ __align__(16) unsigned short sA2[2][128 * 64];  // 2 x 16KB
  __shared__ __align__(16) unsigned short sB2[2][64 * 64];   // 2 x 8KB
  const int tid = threadIdx.x;
  const int wave = tid >> 6, lane = tid & 63;
  const int quad = lane >> 4, l16 = lane & 15;
  const int wx = wave & 1, wy = wave >> 1;
  const int n0 = blockIdx.x * 64, m0 = blockIdx.y * 128;

  f32x4 acc[4][2];
  for (int mt = 0; mt < 4; ++mt)
    for (int nt = 0; nt < 2; ++nt) acc[mt][nt] = (f32x4){0.f, 0.f, 0.f, 0.f};

  const int rw8 = lane >> 3;
  const int cls = ((lane & 7) ^ (lane >> 3)) * 8;
  const int sw = l16 & 7;

#define O_ISSUE(BUF, K0)                                                       \
  _Pragma("unroll") for (int j = 0; j < 4; ++j) {                              \
    int ch = wave * 4 + j;                                                     \
    gload16(A + (size_t)(m0 + ch * 8 + rw8) * D_FEAT + (K0) + cls,             \
            &sA2[BUF][ch * 512]);                                              \
  }                                                                            \
  _Pragma("unroll") for (int j = 0; j < 2; ++j) {                              \
    int ch = wave * 2 + j;                                                     \
    gload16(Bt + (size_t)(n0 + ch * 8 + rw8) * D_FEAT + (K0) + cls,            \
            &sB2[BUF][ch * 512]);                                              \
  }

#define O_COMP(BUF)                                                           \
  {                                                                            \
    const unsigned short* sA = &sA2[BUF][0];                                   \
    const unsigned short* sB = &sB2[BUF][0];                                   \
    s16x8 af[2][4], bfr[2][2];                                                 \
    _Pragma("unroll") for (int kk = 0; kk < 2; ++kk) {                         \
      int c = ((kk * 4 + quad) ^ sw) * 8;                                      \
      _Pragma("unroll") for (int mt = 0; mt < 4; ++mt)                         \
        af[kk][mt] = *(const s16x8*)(sA + (wy * 64 + mt * 16 + l16) * 64 + c); \
      _Pragma("unroll") for (int nt = 0; nt < 2; ++nt)                         \
        bfr[kk][nt] = *(const s16x8*)(sB + (wx * 32 + nt * 16 + l16) * 64 + c);\
    }                                                                          \
    _Pragma("unroll") for (int kk = 0; kk < 2; ++kk)                           \
      _Pragma("unroll") for (int mt = 0; mt < 4; ++mt)                         \
        _Pragma("unroll") for (int nt = 0; nt < 2; ++nt)                       \
          acc[mt][nt] = mfma16(af[kk][mt], bfr[kk][nt], acc[mt][nt]);          \
  }

#define GSYNC(N)                                                               \
  asm volatile("s_waitcnt vmcnt(" #N ")" ::: "memory");                        \
  __builtin_amdgcn_s_barrier();                                               \
  __builtin_amdgcn_sched_barrier(0);

  O_ISSUE(0, 0);
  O_ISSUE(1, 64);
  for (int t2 = 0; t2 < 14; t2 += 2) {
    GSYNC(6);
    O_COMP(0);
    __builtin_amdgcn_s_barrier();
    __builtin_amdgcn_sched_barrier(0);
    O_ISSUE(0, (t2 + 2) * 64);
    GSYNC(6);
    O_COMP(1);
    __builtin_amdgcn_s_barrier();
    __builtin_amdgcn_sched_barrier(0);
    O_ISSUE(1, (t2 + 3) * 64);
  }
  GSYNC(6);
  O_COMP(0);
  GSYNC(0);
  O_COMP(1);
#undef O_ISSUE
#undef O_COMP
#undef GSYNC

  for (int mt = 0; mt < 4; ++mt)
    for (int nt = 0; nt < 2; ++nt) {
      int col = n0 + wx * 32 + nt * 16 + l16;
      float bcol = bias[col];
      for (int r = 0; r < 4; ++r) {
        int row = m0 + wy * 64 + mt * 16 + quad * 4 + r;
        Cout[(size_t)row * D_FEAT + col] =
            acc[mt][nt][r] + bcol + resid[(size_t)row * D_FEAT + col];
      }
    }
}

// ---------------- flash attention, split-S partial pass ----------------
// (r7 verified version, unchanged: cross-tile pipeline, 4x8KB bufs,
// counted vmcnt(2), raw barriers + sched_barrier(0). Plateaued at ~45us.)
__global__ __launch_bounds__(256, 3) void flash_part(
    const unsigned short* __restrict__ Qp,
    const unsigned short* __restrict__ Kp,
    const unsigned short* __restrict__ Vt,
    unsigned short* __restrict__ Opart,   // [z][bh][tok][dv] fp16
    float* __restrict__ L)                // [z][bh][tok]
{
  __shared__ __align__(16) unsigned short sB4[4][4096];

  const int tid = threadIdx.x;
  const int wave = tid >> 6, lane = tid & 63;
  const int l32 = lane & 31, h = lane >> 5;

  const int blk = blockIdx.x;              // 1024 blocks
  const int xcd = blk & 7, jj = blk >> 3;
  const int grp = xcd * 8 + (jj >> 4);     // (bh,z) group 0..63
  const int q0 = (jj & 15) * 128;
  const int bh = grp & 31, z = grp >> 5;
  const int b = bh >> 4, hd = bh & 15;
  const int kbase = z * (SEQ / 2);
  const size_t base = (size_t)b * SEQ * D_FEAT + (size_t)hd * DK;
  const unsigned short* vt = Vt + (size_t)bh * 64 * SEQ;

  const int qrow = wave * 32 + l32;

  const unsigned short* qptr = Qp + base + (size_t)(q0 + qrow) * D_FEAT;
  s16x8 bq[4];
#pragma unroll
  for (int s = 0; s < 4; ++s)
    bq[s] = *(const s16x8*)(qptr + (2 * s + h) * 8);

  const int krow = tid >> 3;
  const unsigned short* kPtr =
      Kp + base + (size_t)(kbase + krow) * D_FEAT + (((tid & 7) ^ (krow & 7)) * 8);
  const int vrow = tid >> 2;
  const unsigned short* vPtr =
      vt + (size_t)vrow * SEQ + kbase + (((tid & 3) ^ ((tid >> 3) & 3)) * 8);

  const int kdst = wave * 512;
#pragma unroll
  for (int pb = 0; pb < 2; ++pb) {
    gload16(kPtr, &sB4[pb][kdst]);
    gload16(vPtr, &sB4[pb][2048 + kdst]);
    kPtr += 32 * D_FEAT; vPtr += 32;
  }

  f32x16 o0, o1, stE, stO;
#pragma unroll
  for (int r = 0; r < 16; ++r) { o0[r] = 0.f; o1[r] = 0.f; }
  float lsA = 0.f, lsB = 0.f;

  const int kxor = l32 & 7;
  const int vxor = (l32 >> 1) & 3;

#define QK_TILE(BUF, ST)                                                       \
  {                                                                            \
    const unsigned short* bK = &sB4[BUF][0];                                   \
    _Pragma("unroll") for (int r = 0; r < 16; ++r) ST[r] = 0.f;                \
    __builtin_amdgcn_s_setprio(1);                                            \
    _Pragma("unroll") for (int s = 0; s < 4; ++s) {                            \
      s16x8 a = *(const s16x8*)(bK + l32 * 64 + (((2 * s + h) ^ kxor) * 8));   \
      ST = mfma32(a, bq[s], ST);                                               \
    }                                                                          \
    __builtin_amdgcn_s_setprio(0);                                            \
  }

#define SMPV_TILE(BUFV, ST)                                                    \
  {                                                                            \
    const unsigned short* bV = &sB4[BUFV][2048];                               \
    unsigned int c[8];                                                         \
    _Pragma("unroll") for (int i = 0; i < 8; ++i) {                            \
      float e0 = fexp2(ST[2 * i]);                                             \
      float e1 = fexp2(ST[2 * i + 1]);                                         \
      lsA += e0; lsB += e1;                                                    \
      c[i] = cvtpk(e0, e1);                                                    \
    }                                                                          \
    swap32(c[0], c[2]); swap32(c[1], c[3]);                                    \
    swap32(c[4], c[6]); swap32(c[5], c[7]);                                    \
    s16x8 bp0 = mk8(c[0], c[1], c[2], c[3]);                                   \
    s16x8 bp1 = mk8(c[4], c[5], c[6], c[7]);                                   \
    __builtin_amdgcn_s_setprio(1);                                            \
    _Pragma("unroll") for (int kk = 0; kk < 2; ++kk) {                         \
      int cs = ((2 * kk + h) ^ vxor) * 8;                                      \
      s16x8 av0 = *(const s16x8*)(bV + l32 * 32 + cs);                         \
      s16x8 av1 = *(const s16x8*)(bV + (32 + l32) * 32 + cs);                  \
      s16x8 bp = kk ? bp1 : bp0;                                               \
      o0 = mfma32(av0, bp, o0);                                                \
      o1 = mfma32(av1, bp, o1);                                                \
    }                                                                          \
    __builtin_amdgcn_s_setprio(0);                                            \
  }

#define SYNC2                                                                  \
  asm volatile("s_waitcnt vmcnt(2)" ::: "memory");                             \
  __builtin_amdgcn_s_barrier();                                               \
  __builtin_amdgcn_sched_barrier(0);
#define ISSUE(NXT)                                                             \
  gload16(kPtr, &sB4[NXT][kdst]);                                              \
  gload16(vPtr, &sB4[NXT][2048 + kdst]);                                       \
  kPtr += 32 * D_FEAT; vPtr += 32;

  SYNC2; ISSUE(2); QK_TILE(0, stE);
  SYNC2; ISSUE(3); QK_TILE(1, stO); SMPV_TILE(0, stE);
  SYNC2; ISSUE(0); QK_TILE(2, stE); SMPV_TILE(1, stO);
  SYNC2; ISSUE(1); QK_TILE(3, stO); SMPV_TILE(2, stE);
  for (int g6 = 0; g6 < 6; ++g6) {
    SYNC2; ISSUE(2); QK_TILE(0, stE); SMPV_TILE(3, stO);
    SYNC2; ISSUE(3); QK_TILE(1, stO); SMPV_TILE(0, stE);
    SYNC2; ISSUE(0); QK_TILE(2, stE); SMPV_TILE(1, stO);
    SYNC2; ISSUE(1); QK_TILE(3, stO); SMPV_TILE(2, stE);
  }
  SYNC2; ISSUE(2); QK_TILE(0, stE); SMPV_TILE(3, stO);
  SYNC2; ISSUE(3); QK_TILE(1, stO); SMPV_TILE(0, stE);
  SYNC2;           QK_TILE(2, stE); SMPV_TILE(1, stO);
  asm volatile("s_waitcnt vmcnt(0)" ::: "memory");
  __builtin_amdgcn_s_barrier();
  __builtin_amdgcn_sched_barrier(0);
  QK_TILE(3, stO); SMPV_TILE(2, stE);
  SMPV_TILE(3, stO);
#undef QK_TILE
#undef SMPV_TILE
#undef SYNC2
#undef ISSUE

  float lsum = lsA + lsB;
  lsum += __shfl_xor(lsum, 32, 64);
  const size_t trow = (size_t)(z * 32 + bh) * SEQ + (q0 + qrow);
  unsigned short* orow = Opart + trow * 64;
#pragma unroll
  for (int g = 0; g < 4; ++g) {
    u16x4 ov;
    for (int r = 0; r < 4; ++r) ov[r] = f2h(o0[4 * g + r]);
    *(u16x4*)(orow + 8 * g + 4 * h) = ov;
  }
#pragma unroll
  for (int g = 0; g < 4; ++g) {
    u16x4 ov;
    for (int r = 0; r < 4; ++r) ov[r] = f2h(o1[4 * g + r]);
    *(u16x4*)(orow + 32 + 8 * g + 4 * h) = ov;
  }
  if (h == 0) L[trow] = lsum;
}

// ---------------- combine the two key-halves -> ctx (bf16) ----------------
__global__ __launch_bounds__(256) void combine_kernel(
    const unsigned short* __restrict__ Opart, const float* __restrict__ L,
    unsigned short* __restrict__ ctx)
{
  const int idx = blockIdx.x * 256 + threadIdx.x;   // 1M total
  const int dq = idx & 15;                          // dv group of 4
  const int trow = idx >> 4;                        // bh*SEQ + tok
  const int bh = trow >> 11, tok = trow & 2047;
  const int b = bh >> 4, h = bh & 15;
  const int HS = 32 * SEQ;                          // half stride (rows)

  float inv = __builtin_amdgcn_rcpf(L[trow] + L[HS + trow]);

  u16x4 p0 = *(const u16x4*)(Opart + (size_t)trow * 64 + dq * 4);
  u16x4 p1 = *(const u16x4*)(Opart + ((size_t)HS + trow) * 64 + dq * 4);
  u16x4 o;
  for (int r = 0; r < 4; ++r)
    o[r] = f2bf((h2f(p0[r]) + h2f(p1[r])) * inv);
  *(u16x4*)(ctx + (size_t)b * SEQ * D_FEAT + (size_t)tok * D_FEAT + h * 64 + dq * 4) = o;
}

// ---------------- LayerNorm over last dim (1024) ----------------
__global__ __launch_bounds__(256) void ln_kernel(
    const float* __restrict__ x, const float* __restrict__ gamma,
    const float* __restrict__ beta, float* __restrict__ out)
{
  const int row = blockIdx.x, tid = threadIdx.x;
  const int wave = tid >> 6, lane = tid & 63;
  const float* xr = x + (size_t)row * D_FEAT;
  float4 v = ((const float4*)xr)[tid];
  float s  = v.x + v.y + v.z + v.w;
  float ss = v.x * v.x + v.y * v.y + v.z * v.z + v.w * v.w;
  for (int off = 1; off < 64; off <<= 1) {
    s  += __shfl_xor(s,  off, 64);
    ss += __shfl_xor(ss, off, 64);
  }
  __shared__ float red[8];
  if (lane == 0) { red[wave] = s; red[wave + 4] = ss; }
  __syncthreads();
  s  = red[0] + red[1] + red[2] + red[3];
  ss = red[4] + red[5] + red[6] + red[7];
  float mean = s * (1.f / D_FEAT);
  float var  = ss * (1.f / D_FEAT) - mean * mean;
  float rstd = rsqrtf(var + 1e-6f);
  float4 g  = ((const float4*)gamma)[tid];
  float4 bt = ((const float4*)beta)[tid];
  float4 o;
  o.x = (v.x - mean) * rstd * g.x + bt.x;
  o.y = (v.y - mean) * rstd * g.y + bt.y;
  o.z = (v.z - mean) * rstd * g.z + bt.z;
  o.w = (v.w - mean) * rstd * g.w + bt.w;
  ((float4*)(out + (size_t)row * D_FEAT))[tid] = o;
}

extern "C" void kernel_launch(void* const* d_in, const int* in_sizes, int n_in,
                              void* d_out, int out_size, void* d_ws, size_t ws_size,
                              hipStream_t stream) {
  const float* q     = (const float*)d_in[0];
  const float* k     = (const float*)d_in[1];
  const float* v     = (const float*)d_in[2];
  const float* Wq    = (const float*)d_in[3];
  const float* bq    = (const float*)d_in[4];
  const float* Wk    = (const float*)d_in[5];
  const float* bk    = (const float*)d_in[6];
  const float* Wv    = (const float*)d_in[7];
  const float* bv    = (const float*)d_in[8];
  const float* Wo    = (const float*)d_in[9];
  const float* bo    = (const float*)d_in[10];
  const float* gamma = (const float*)d_in[11];
  const float* beta  = (const float*)d_in[12];

  char* w = (char*)d_ws;
  const size_t MB = 1u << 20;
  unsigned short* qb    = (unsigned short*)(w + 0 * MB);
  unsigned short* kb    = (unsigned short*)(w + 8 * MB);
  unsigned short* vb    = (unsigned short*)(w + 16 * MB);
  unsigned short* WT    = (unsigned short*)(w + 24 * MB);
  unsigned short* Wot   = (unsigned short*)(w + 30 * MB);
  unsigned short* Qp    = (unsigned short*)(w + 32 * MB);
  unsigned short* Kp    = (unsigned short*)(w + 40 * MB);
  unsigned short* Vt    = (unsigned short*)(w + 48 * MB);  // [bh][dv][tok]
  unsigned short* ctx   = (unsigned short*)(w + 56 * MB);
  float*          tmp   = (float*)(w + 64 * MB);           // 16 MB
  unsigned short* Opart = (unsigned short*)(w + 0 * MB);   // 16 MB fp16 (aliases qb/kb)
  float*          L     = (float*)(w + 16 * MB);           // 0.5 MB (aliases vb)

  prep_kernel<<<16384, 256, 0, stream>>>(q, k, v, Wq, Wk, Wv, Wo, qb, kb, vb, WT, Wot);

  gemm_qkv<<<dim3(24, 32), 256, 0, stream>>>(qb, kb, vb, WT, bq, bk, bv, Qp, Kp, Vt);

  flash_part<<<1024, 256, 0, stream>>>(Qp, Kp, Vt, Opart, L);

  combine_kernel<<<4096, 256, 0, stream>>>(Opart, L, ctx);

  gemm_o<<<dim3(16, 32), 256, 0, stream>>>(ctx, Wot, bo, v, tmp);

  ln_kernel<<<NTOK, 256, 0, stream>>>(tmp, gamma, beta, (float*)d_out);
}